// Round 1
// baseline (938.678 us; speedup 1.0000x reference)
//
#include <hip/hip_runtime.h>
#include <hip/hip_bf16.h>
#include <math.h>

// Problem constants (from reference setup_inputs)
#define C_DIM 256
#define H_HEADS 8
#define B_GRAPHS 2048
#define NPG 128
#define N_NODES (B_GRAPHS * NPG)   // 262144
#define EPS 1e-5f
#define SCALE_ATT 0.17677669529663687f   // 1/sqrt(32)

// -------- workspace layout (float offsets) --------
#define OFF_H1   0UL                       // 67108864  (N*C fp32)
#define OFF_W1T  67108864UL                // 65536
#define OFF_WKE  67174400UL                // 2048  wk_eff[head*256+c']
#define OFF_LB   67176448UL                // 8
#define OFF_WFD  67176456UL                // 2048  wfold[c*8+head]
#define OFF_BFD  67178504UL                // 8
#define OFF_WOR  67178512UL                // 256
#define OFF_V    67178768UL                // 2048  V[head*256+c']
#define OFF_G    67180816UL                // 2048  G[c*8+head]
#define OFF_C0   67182864UL                // 1 (next offset padded to keep 16B alignment of later arrays)
#define OFF_PS   67182868UL                // 256
#define OFF_PS2  67183124UL                // 256
#define OFF_SC   67183380UL                // 256
#define OFF_SH   67183636UL                // 256
// total ~67.18M floats ~= 256.3 MiB

// ---------------- prep kernels ----------------

// qh = rowsum(Wq)+bq ; wk_eff[head,c'] = scale * sum_d Wk[head*32+d,c']*qh[head*32+d]
// lbias[head] = scale * sum_d bk[...]*qh[...] ; wor[j] = sum_j2 Wo[j2,j]*Wr[j2]
__global__ __launch_bounds__(256) void prep1_kernel(
    const float* __restrict__ Wq, const float* __restrict__ bq,
    const float* __restrict__ Wk, const float* __restrict__ bk,
    const float* __restrict__ Wo, const float* __restrict__ Wr,
    float* __restrict__ wk_eff, float* __restrict__ lbias, float* __restrict__ wor)
{
    __shared__ float qhS[256];
    __shared__ float WrS[256];
    const int t = threadIdx.x;
    {
        float s = bq[t];
        const float* row = Wq + (size_t)t * 256;
        for (int c = 0; c < 256; c += 4) {
            float4 v = *(const float4*)&row[c];
            s += v.x + v.y + v.z + v.w;
        }
        qhS[t] = s;
        WrS[t] = Wr[t];
    }
    __syncthreads();
    for (int it = 0; it < 8; ++it) {
        int idx = t + it * 256;
        int head = idx >> 8, c = idx & 255;
        float acc = 0.f;
        #pragma unroll 4
        for (int d = 0; d < 32; ++d)
            acc = fmaf(Wk[(size_t)(head * 32 + d) * 256 + c], qhS[head * 32 + d], acc);
        wk_eff[head * 256 + c] = acc * SCALE_ATT;
    }
    if (t < 8) {
        float acc = 0.f;
        for (int d = 0; d < 32; ++d) acc = fmaf(bk[t * 32 + d], qhS[t * 32 + d], acc);
        lbias[t] = acc * SCALE_ATT;
    }
    {
        float acc = 0.f;
        for (int j2 = 0; j2 < 256; ++j2)
            acc = fmaf(Wo[(size_t)j2 * 256 + t], WrS[j2], acc);
        wor[t] = acc;
    }
}

// per-head: wfold[c*8+head] = sum_c' W2[c',c]*wk_eff[head,c']
//           bfold[head] = lbias[head] + sum_c' b2[c']*wk_eff[head,c']
//           V[head,c'] = sum_{d} Wv[head*32+d, c'] * wor[head*32+d]
__global__ __launch_bounds__(256) void prep2_kernel(
    const float* __restrict__ W2, const float* __restrict__ b2,
    const float* __restrict__ Wv, const float* __restrict__ wk_eff,
    const float* __restrict__ lbias, const float* __restrict__ wor_g,
    float* __restrict__ wfold, float* __restrict__ bfold, float* __restrict__ V_g)
{
    __shared__ float wkS[256];
    const int t = threadIdx.x, head = blockIdx.x;
    wkS[t] = wk_eff[head * 256 + t];
    __syncthreads();
    float acc = 0.f;
    #pragma unroll 4
    for (int cp = 0; cp < 256; ++cp)
        acc = fmaf(W2[(size_t)cp * 256 + t], wkS[cp], acc);
    wfold[t * 8 + head] = acc;
    float accv = 0.f;
    #pragma unroll 4
    for (int d = 0; d < 32; ++d) {
        int j = head * 32 + d;
        accv = fmaf(Wv[(size_t)j * 256 + t], wor_g[j], accv);
    }
    V_g[head * 256 + t] = accv;
    if (t == 0) {
        float b = lbias[head];
        for (int cp = 0; cp < 256; ++cp) b = fmaf(b2[cp], wkS[cp], b);
        bfold[head] = b;
    }
}

// G[c*8+head] = sum_c' W2[c',c]*V[head,c']
__global__ __launch_bounds__(256) void prep3_kernel(
    const float* __restrict__ W2, const float* __restrict__ V_g, float* __restrict__ G_g)
{
    __shared__ float vS[256];
    const int t = threadIdx.x, head = blockIdx.x;
    vS[t] = V_g[head * 256 + t];
    __syncthreads();
    float acc = 0.f;
    #pragma unroll 4
    for (int cp = 0; cp < 256; ++cp)
        acc = fmaf(W2[(size_t)cp * 256 + t], vS[cp], acc);
    G_g[t * 8 + head] = acc;
}

// c0 = sum_{head,c'} b2[c']*V[head,c'] + sum_j bv[j]*wor[j] + sum_j2 bo[j2]*Wr[j2] + br
__global__ __launch_bounds__(256) void prep4_kernel(
    const float* __restrict__ b2, const float* __restrict__ bv,
    const float* __restrict__ bo, const float* __restrict__ Wr,
    const float* __restrict__ br, const float* __restrict__ V_g,
    const float* __restrict__ wor, float* __restrict__ c0)
{
    __shared__ float red[256];
    const int t = threadIdx.x;
    float vs = 0.f;
    #pragma unroll
    for (int h = 0; h < 8; ++h) vs += V_g[h * 256 + t];
    red[t] = b2[t] * vs + bv[t] * wor[t] + bo[t] * Wr[t];
    __syncthreads();
    for (int s = 128; s > 0; s >>= 1) {
        if (t < s) red[t] += red[t + s];
        __syncthreads();
    }
    if (t == 0) c0[0] = red[0] + br[0];
}

// W1T[k*256+j] = W1[j*256+k]
__global__ __launch_bounds__(256) void transpose_kernel(
    const float* __restrict__ W1, float* __restrict__ W1T)
{
    __shared__ float tile[64 * 65];
    const int t = threadIdx.x;
    const int ti = blockIdx.x >> 2, tj = blockIdx.x & 3;
    const int lr = t >> 6, lc = t & 63;
    for (int p = 0; p < 16; ++p) {
        int r = p * 4 + lr;
        tile[r * 65 + lc] = W1[(size_t)(ti * 64 + r) * 256 + tj * 64 + lc];
    }
    __syncthreads();
    for (int p = 0; p < 16; ++p) {
        int r = p * 4 + lr;
        W1T[(size_t)(tj * 64 + r) * 256 + ti * 64 + lc] = tile[lc * 65 + r];
    }
}

// ---------------- GEMM1: h1 = x @ W1^T + b1, plus per-channel sum/sumsq ----------------
// 64 rows x 256 cols per block; 256 threads; 8x8 per thread.
__global__ __launch_bounds__(256) void gemm1_kernel(
    const float* __restrict__ x, const float* __restrict__ W1T,
    const float* __restrict__ b1, float* __restrict__ h1,
    float* __restrict__ psum, float* __restrict__ psum2)
{
    __shared__ float lds[2176 + 8192];   // xsT[32][68] + wt[32][256]  (reused for stats reduce)
    float* xsT = lds;
    float* wt = lds + 2176;
    const int t = threadIdx.x;
    const int tx = t & 31, ty = t >> 5;
    const int g0 = blockIdx.x * 64;

    float acc[8][8];
    #pragma unroll
    for (int u = 0; u < 8; ++u)
        #pragma unroll
        for (int v = 0; v < 8; ++v) acc[u][v] = 0.f;

    for (int kk = 0; kk < 8; ++kk) {
        if (kk) __syncthreads();
        // stage x tile (64 rows x 32 k), transposed into xsT[k][row]
        #pragma unroll
        for (int q = 0; q < 2; ++q) {
            int i4 = t + q * 256;
            int r = i4 >> 3, c4 = (i4 & 7) * 4;
            const float4 v = *(const float4*)&x[(size_t)(g0 + r) * 256 + kk * 32 + c4];
            xsT[(c4 + 0) * 68 + r] = v.x;
            xsT[(c4 + 1) * 68 + r] = v.y;
            xsT[(c4 + 2) * 68 + r] = v.z;
            xsT[(c4 + 3) * 68 + r] = v.w;
        }
        // stage W1T tile (32 k x 256 cols)
        #pragma unroll
        for (int q = 0; q < 8; ++q) {
            int i4 = t + q * 256;
            int r = i4 >> 6, c4 = (i4 & 63) * 4;
            *(float4*)&wt[r * 256 + c4] = *(const float4*)&W1T[(size_t)(kk * 32 + r) * 256 + c4];
        }
        __syncthreads();
        #pragma unroll 4
        for (int k = 0; k < 32; ++k) {
            float a[8], b[8];
            *(float4*)&a[0] = *(const float4*)&xsT[k * 68 + ty * 8];
            *(float4*)&a[4] = *(const float4*)&xsT[k * 68 + ty * 8 + 4];
            *(float4*)&b[0] = *(const float4*)&wt[k * 256 + tx * 8];
            *(float4*)&b[4] = *(const float4*)&wt[k * 256 + tx * 8 + 4];
            #pragma unroll
            for (int u = 0; u < 8; ++u)
                #pragma unroll
                for (int v = 0; v < 8; ++v)
                    acc[u][v] = fmaf(a[u], b[v], acc[u][v]);
        }
    }

    // epilogue: +b1, write h1, per-channel partial stats
    float bb[8];
    *(float4*)&bb[0] = *(const float4*)&b1[tx * 8];
    *(float4*)&bb[4] = *(const float4*)&b1[tx * 8 + 4];
    float s1v[8], s2v[8];
    #pragma unroll
    for (int v = 0; v < 8; ++v) { s1v[v] = 0.f; s2v[v] = 0.f; }
    #pragma unroll
    for (int u = 0; u < 8; ++u) {
        float o[8];
        #pragma unroll
        for (int v = 0; v < 8; ++v) {
            float h = acc[u][v] + bb[v];
            o[v] = h;
            s1v[v] += h;
            s2v[v] += h * h;
        }
        *(float4*)&h1[(size_t)(g0 + ty * 8 + u) * 256 + tx * 8] = *(float4*)&o[0];
        *(float4*)&h1[(size_t)(g0 + ty * 8 + u) * 256 + tx * 8 + 4] = *(float4*)&o[4];
    }
    __syncthreads();
    float* red = lds;          // 2048
    float* red2 = lds + 2048;  // 2048
    #pragma unroll
    for (int v = 0; v < 8; ++v) {
        red[ty * 256 + tx * 8 + v] = s1v[v];
        red2[ty * 256 + tx * 8 + v] = s2v[v];
    }
    __syncthreads();
    float S = 0.f, S2 = 0.f;
    #pragma unroll
    for (int r = 0; r < 8; ++r) {
        S += red[r * 256 + t];
        S2 += red2[r * 256 + t];
    }
    atomicAdd(&psum[t], S);
    atomicAdd(&psum2[t], S2);
}

// sc = gamma*rstd ; sh = beta - mu*gamma*rstd
__global__ __launch_bounds__(256) void stats_kernel(
    const float* __restrict__ psum, const float* __restrict__ psum2,
    const float* __restrict__ gamma, const float* __restrict__ beta,
    float* __restrict__ sc, float* __restrict__ sh)
{
    const int t = threadIdx.x;
    const float invN = 1.0f / (float)N_NODES;
    float S = psum[t], S2 = psum2[t];
    float mu = S * invN;
    float var = S2 * invN - mu * mu;
    float rstd = rsqrtf(var + EPS);
    float g = gamma[t] * rstd;
    sc[t] = g;
    sh[t] = beta[t] - mu * g;
}

// ---------------- fused per-graph kernel ----------------
// one block per graph: logits -> softmax -> A~ -> dot(G) -> tanh
__global__ __launch_bounds__(256, 4) void fused_kernel(
    const float* __restrict__ h1, const float* __restrict__ sc_g,
    const float* __restrict__ sh_g, const float* __restrict__ wfold,
    const float* __restrict__ bfold, const float* __restrict__ G_g,
    const float* __restrict__ c0_g, float* __restrict__ out)
{
    __shared__ float scS[256], shS[256];
    __shared__ float wfS[2048];
    __shared__ float bfS[8];
    __shared__ float logitsS[8 * 129];
    __shared__ float attnS[128 * 8];
    __shared__ float AtS[256 * 8];
    __shared__ float redS[4];

    const int t = threadIdx.x;
    const int g = blockIdx.x;
    const float* hrow = h1 + (size_t)g * NPG * 256;

    scS[t] = sc_g[t];
    shS[t] = sh_g[t];
    #pragma unroll
    for (int q = 0; q < 8; ++q) wfS[t + q * 256] = wfold[t + q * 256];
    if (t < 8) bfS[t] = bfold[t];
    __syncthreads();

    // P2: logits[n, head] = a1[n,:] . wfold[head,:] + bfold[head]
    {
        const int n = t & 127, hg = t >> 7;
        const float* hr = hrow + (size_t)n * 256;
        float f0 = 0.f, f1 = 0.f, f2 = 0.f, f3 = 0.f;
        #pragma unroll 4
        for (int c4 = 0; c4 < 256; c4 += 4) {
            float4 v = *(const float4*)&hr[c4];
            float a0 = fmaxf(fmaf(v.x, scS[c4 + 0], shS[c4 + 0]), 0.f);
            float a1 = fmaxf(fmaf(v.y, scS[c4 + 1], shS[c4 + 1]), 0.f);
            float a2 = fmaxf(fmaf(v.z, scS[c4 + 2], shS[c4 + 2]), 0.f);
            float a3 = fmaxf(fmaf(v.w, scS[c4 + 3], shS[c4 + 3]), 0.f);
            float4 w0 = *(const float4*)&wfS[(c4 + 0) * 8 + hg * 4];
            float4 w1 = *(const float4*)&wfS[(c4 + 1) * 8 + hg * 4];
            float4 w2 = *(const float4*)&wfS[(c4 + 2) * 8 + hg * 4];
            float4 w3 = *(const float4*)&wfS[(c4 + 3) * 8 + hg * 4];
            f0 = fmaf(a0, w0.x, fmaf(a1, w1.x, fmaf(a2, w2.x, fmaf(a3, w3.x, f0))));
            f1 = fmaf(a0, w0.y, fmaf(a1, w1.y, fmaf(a2, w2.y, fmaf(a3, w3.y, f1))));
            f2 = fmaf(a0, w0.z, fmaf(a1, w1.z, fmaf(a2, w2.z, fmaf(a3, w3.z, f2))));
            f3 = fmaf(a0, w0.w, fmaf(a1, w1.w, fmaf(a2, w2.w, fmaf(a3, w3.w, f3))));
        }
        const int hb = hg * 4;
        logitsS[(hb + 0) * 129 + n] = f0 + bfS[hb + 0];
        logitsS[(hb + 1) * 129 + n] = f1 + bfS[hb + 1];
        logitsS[(hb + 2) * 129 + n] = f2 + bfS[hb + 2];
        logitsS[(hb + 3) * 129 + n] = f3 + bfS[hb + 3];
    }
    __syncthreads();

    // P3: softmax per (head) over 128 nodes; 32 threads per head
    {
        const int head = t >> 5, j = t & 31;
        float l0 = logitsS[head * 129 + j];
        float l1 = logitsS[head * 129 + j + 32];
        float l2 = logitsS[head * 129 + j + 64];
        float l3 = logitsS[head * 129 + j + 96];
        float m = fmaxf(fmaxf(l0, l1), fmaxf(l2, l3));
        for (int s = 16; s > 0; s >>= 1) m = fmaxf(m, __shfl_xor(m, s, 32));
        float p0 = expf(l0 - m), p1 = expf(l1 - m), p2 = expf(l2 - m), p3 = expf(l3 - m);
        float sum = p0 + p1 + p2 + p3;
        for (int s = 16; s > 0; s >>= 1) sum += __shfl_xor(sum, s, 32);
        float inv = 1.0f / sum;
        attnS[(j + 0) * 8 + head] = p0 * inv;
        attnS[(j + 32) * 8 + head] = p1 * inv;
        attnS[(j + 64) * 8 + head] = p2 * inv;
        attnS[(j + 96) * 8 + head] = p3 * inv;
    }
    __syncthreads();

    // P4: A~[head][c=t] = sum_n attn[n,head]*a1[n,t]   (re-read h1 coalesced)
    {
        float acc[8];
        #pragma unroll
        for (int h = 0; h < 8; ++h) acc[h] = 0.f;
        const float scv = scS[t], shv = shS[t];
        #pragma unroll 2
        for (int n = 0; n < 128; ++n) {
            float hv = hrow[(size_t)n * 256 + t];
            float a = fmaxf(fmaf(hv, scv, shv), 0.f);
            float4 w0 = *(const float4*)&attnS[n * 8];
            float4 w1 = *(const float4*)&attnS[n * 8 + 4];
            acc[0] = fmaf(a, w0.x, acc[0]);
            acc[1] = fmaf(a, w0.y, acc[1]);
            acc[2] = fmaf(a, w0.z, acc[2]);
            acc[3] = fmaf(a, w0.w, acc[3]);
            acc[4] = fmaf(a, w1.x, acc[4]);
            acc[5] = fmaf(a, w1.y, acc[5]);
            acc[6] = fmaf(a, w1.z, acc[6]);
            acc[7] = fmaf(a, w1.w, acc[7]);
        }
        #pragma unroll
        for (int h = 0; h < 8; ++h) AtS[t * 8 + h] = acc[h];
    }
    __syncthreads();

    // P6: r = sum_{head,c} A~[head][c]*G[head][c] + c0 ; out = tanh(r)
    {
        float4 a0 = *(const float4*)&AtS[t * 8];
        float4 a1 = *(const float4*)&AtS[t * 8 + 4];
        float4 g0 = *(const float4*)&G_g[t * 8];
        float4 g1 = *(const float4*)&G_g[t * 8 + 4];
        float term = a0.x * g0.x + a0.y * g0.y + a0.z * g0.z + a0.w * g0.w +
                     a1.x * g1.x + a1.y * g1.y + a1.z * g1.z + a1.w * g1.w;
        for (int s = 32; s > 0; s >>= 1) term += __shfl_xor(term, s, 64);
        if ((t & 63) == 0) redS[t >> 6] = term;
        __syncthreads();
        if (t == 0) out[g] = tanhf(redS[0] + redS[1] + redS[2] + redS[3] + c0_g[0]);
    }
}

// ---------------- launch ----------------
extern "C" void kernel_launch(void* const* d_in, const int* in_sizes, int n_in,
                              void* d_out, int out_size, void* d_ws, size_t ws_size,
                              hipStream_t stream)
{
    (void)in_sizes; (void)n_in; (void)out_size; (void)ws_size;
    const float* x     = (const float*)d_in[0];
    // d_in[1] = batch (unused: seg = n >> 7 by construction), d_in[2] = num_graphs
    const float* W1    = (const float*)d_in[3];
    const float* b1    = (const float*)d_in[4];
    const float* gamma = (const float*)d_in[5];
    const float* beta  = (const float*)d_in[6];
    const float* W2    = (const float*)d_in[7];
    const float* b2    = (const float*)d_in[8];
    const float* Wq    = (const float*)d_in[9];
    const float* bq    = (const float*)d_in[10];
    const float* Wk    = (const float*)d_in[11];
    const float* bk    = (const float*)d_in[12];
    const float* Wv    = (const float*)d_in[13];
    const float* bv    = (const float*)d_in[14];
    const float* Wo    = (const float*)d_in[15];
    const float* bo    = (const float*)d_in[16];
    const float* Wr    = (const float*)d_in[17];
    const float* br    = (const float*)d_in[18];

    float* ws     = (float*)d_ws;
    float* h1     = ws + OFF_H1;
    float* W1T    = ws + OFF_W1T;
    float* wk_eff = ws + OFF_WKE;
    float* lbias  = ws + OFF_LB;
    float* wfold  = ws + OFF_WFD;
    float* bfold  = ws + OFF_BFD;
    float* wor    = ws + OFF_WOR;
    float* V_g    = ws + OFF_V;
    float* G_g    = ws + OFF_G;
    float* c0     = ws + OFF_C0;
    float* psum   = ws + OFF_PS;
    float* psum2  = ws + OFF_PS2;
    float* sc     = ws + OFF_SC;
    float* sh     = ws + OFF_SH;

    hipMemsetAsync((void*)psum, 0, 512 * sizeof(float), stream);

    hipLaunchKernelGGL(prep1_kernel, dim3(1), dim3(256), 0, stream,
                       Wq, bq, Wk, bk, Wo, Wr, wk_eff, lbias, wor);
    hipLaunchKernelGGL(transpose_kernel, dim3(16), dim3(256), 0, stream, W1, W1T);
    hipLaunchKernelGGL(prep2_kernel, dim3(8), dim3(256), 0, stream,
                       W2, b2, Wv, wk_eff, lbias, wor, wfold, bfold, V_g);
    hipLaunchKernelGGL(prep3_kernel, dim3(8), dim3(256), 0, stream, W2, V_g, G_g);
    hipLaunchKernelGGL(prep4_kernel, dim3(1), dim3(256), 0, stream,
                       b2, bv, bo, Wr, br, V_g, wor, c0);
    hipLaunchKernelGGL(gemm1_kernel, dim3(N_NODES / 64), dim3(256), 0, stream,
                       x, W1T, b1, h1, psum, psum2);
    hipLaunchKernelGGL(stats_kernel, dim3(1), dim3(256), 0, stream,
                       psum, psum2, gamma, beta, sc, sh);
    hipLaunchKernelGGL(fused_kernel, dim3(B_GRAPHS), dim3(256), 0, stream,
                       h1, sc, sh, wfold, bfold, G_g, c0, (float*)d_out);
}

// Round 2
// 647.008 us; speedup vs baseline: 1.4508x; 1.4508x over previous
//
#include <hip/hip_runtime.h>
#include <hip/hip_bf16.h>
#include <math.h>

#define C_DIM 256
#define H_HEADS 8
#define B_GRAPHS 2048
#define NPG 128
#define N_NODES (B_GRAPHS * NPG)   // 262144
#define EPS 1e-5f
#define SCALE_ATT 0.17677669529663687f   // 1/sqrt(32)

typedef short bf16x8 __attribute__((ext_vector_type(8)));
typedef float f32x4 __attribute__((ext_vector_type(4)));

__device__ __forceinline__ unsigned short f2bf(float f) {
    __hip_bfloat16 h = __float2bfloat16(f);
    union { __hip_bfloat16 h; unsigned short u; } cv; cv.h = h; return cv.u;
}
__device__ __forceinline__ float bf2f(unsigned short u) {
    union { unsigned int i; float f; } v; v.i = ((unsigned int)u) << 16; return v.f;
}

// ---------------- prep kernels ----------------

// qh = rowsum(Wq)+bq ; wk_eff[head,c'] = scale * sum_d Wk[head*32+d,c']*qh[head*32+d]
// lbias[head] = scale * sum_d bk*qh ; wor[j] = sum_j2 Wo[j2,j]*Wr[j2]
__global__ __launch_bounds__(256) void prep1_kernel(
    const float* __restrict__ Wq, const float* __restrict__ bq,
    const float* __restrict__ Wk, const float* __restrict__ bk,
    const float* __restrict__ Wo, const float* __restrict__ Wr,
    float* __restrict__ wk_eff, float* __restrict__ lbias, float* __restrict__ wor)
{
    __shared__ float qhS[256];
    __shared__ float WrS[256];
    const int t = threadIdx.x;
    {
        float s = bq[t];
        const float* row = Wq + (size_t)t * 256;
        for (int c = 0; c < 256; c += 4) {
            float4 v = *(const float4*)&row[c];
            s += v.x + v.y + v.z + v.w;
        }
        qhS[t] = s;
        WrS[t] = Wr[t];
    }
    __syncthreads();
    for (int it = 0; it < 8; ++it) {
        int idx = t + it * 256;
        int head = idx >> 8, c = idx & 255;
        float acc = 0.f;
        #pragma unroll 4
        for (int d = 0; d < 32; ++d)
            acc = fmaf(Wk[(size_t)(head * 32 + d) * 256 + c], qhS[head * 32 + d], acc);
        wk_eff[head * 256 + c] = acc * SCALE_ATT;
    }
    if (t < 8) {
        float acc = 0.f;
        for (int d = 0; d < 32; ++d) acc = fmaf(bk[t * 32 + d], qhS[t * 32 + d], acc);
        lbias[t] = acc * SCALE_ATT;
    }
    {
        float acc = 0.f;
        for (int j2 = 0; j2 < 256; ++j2)
            acc = fmaf(Wo[(size_t)j2 * 256 + t], WrS[j2], acc);
        wor[t] = acc;
    }
}

// wfT[head][c] = sum_c' W2[c',c]*wk_eff[head,c'];  bfold[head];  V[head,c']
__global__ __launch_bounds__(256) void prep2_kernel(
    const float* __restrict__ W2, const float* __restrict__ b2,
    const float* __restrict__ Wv, const float* __restrict__ wk_eff,
    const float* __restrict__ lbias, const float* __restrict__ wor_g,
    float* __restrict__ wfT, float* __restrict__ bfold, float* __restrict__ V_g)
{
    __shared__ float wkS[256];
    const int t = threadIdx.x, head = blockIdx.x;
    wkS[t] = wk_eff[head * 256 + t];
    __syncthreads();
    float acc = 0.f;
    #pragma unroll 4
    for (int cp = 0; cp < 256; ++cp)
        acc = fmaf(W2[(size_t)cp * 256 + t], wkS[cp], acc);
    wfT[head * 256 + t] = acc;
    float accv = 0.f;
    #pragma unroll 4
    for (int d = 0; d < 32; ++d) {
        int j = head * 32 + d;
        accv = fmaf(Wv[(size_t)j * 256 + t], wor_g[j], accv);
    }
    V_g[head * 256 + t] = accv;
    if (t == 0) {
        float b = lbias[head];
        for (int cp = 0; cp < 256; ++cp) b = fmaf(b2[cp], wkS[cp], b);
        bfold[head] = b;
    }
}

// G[c*8+head] = sum_c' W2[c',c]*V[head,c']
__global__ __launch_bounds__(256) void prep3_kernel(
    const float* __restrict__ W2, const float* __restrict__ V_g, float* __restrict__ G_g)
{
    __shared__ float vS[256];
    const int t = threadIdx.x, head = blockIdx.x;
    vS[t] = V_g[head * 256 + t];
    __syncthreads();
    float acc = 0.f;
    #pragma unroll 4
    for (int cp = 0; cp < 256; ++cp)
        acc = fmaf(W2[(size_t)cp * 256 + t], vS[cp], acc);
    G_g[t * 8 + head] = acc;
}

// c0 = sum b2*V + sum bv*wor + sum bo*Wr + br
__global__ __launch_bounds__(256) void prep4_kernel(
    const float* __restrict__ b2, const float* __restrict__ bv,
    const float* __restrict__ bo, const float* __restrict__ Wr,
    const float* __restrict__ br, const float* __restrict__ V_g,
    const float* __restrict__ wor, float* __restrict__ c0)
{
    __shared__ float red[256];
    const int t = threadIdx.x;
    float vs = 0.f;
    #pragma unroll
    for (int h = 0; h < 8; ++h) vs += V_g[h * 256 + t];
    red[t] = b2[t] * vs + bv[t] * wor[t] + bo[t] * Wr[t];
    __syncthreads();
    for (int s = 128; s > 0; s >>= 1) {
        if (t < s) red[t] += red[t + s];
        __syncthreads();
    }
    if (t == 0) c0[0] = red[0] + br[0];
}

// W1 fp32 -> bf16 (row-major [j][k], which is exactly the MFMA B-operand feed layout)
__global__ __launch_bounds__(256) void w1cvt_kernel(
    const float* __restrict__ W1, unsigned short* __restrict__ W1bf)
{
    int i = blockIdx.x * 256 + threadIdx.x;
    W1bf[i] = f2bf(W1[i]);
}

// ---------------- GEMM1 (MFMA bf16): h1 = x @ W1^T (b1 cancels through LN) ----------------
// 128 rows x 256 cols per block, BK=32, 8 k-iters. h1 stored bf16. Per-wave channel partials.
__global__ __launch_bounds__(256) void gemm1_kernel(
    const float* __restrict__ x, const unsigned short* __restrict__ W1bf,
    unsigned short* __restrict__ h1bf,
    float* __restrict__ parts1, float* __restrict__ parts2)
{
    __shared__ unsigned short Alds[128 * 40];   // 10 KB, row stride 40 bf16
    __shared__ unsigned short Blds[256 * 40];   // 20.5 KB
    const int t = threadIdx.x;
    const int lane = t & 63, w = t >> 6;
    const int l15 = lane & 15, kg = lane >> 4;
    const size_t n0 = (size_t)blockIdx.x * 128;

    f32x4 acc[2][16];
    #pragma unroll
    for (int mt = 0; mt < 2; ++mt)
        #pragma unroll
        for (int nt = 0; nt < 16; ++nt)
            acc[mt][nt] = (f32x4){0.f, 0.f, 0.f, 0.f};

    for (int kk = 0; kk < 8; ++kk) {
        if (kk) __syncthreads();
        #pragma unroll
        for (int p = 0; p < 4; ++p) {
            int i = p * 256 + t;
            {   // A: x chunk 128 rows x 32 k fp32 -> bf16 LDS
                int row = i >> 3, kq = i & 7;
                float4 v = *(const float4*)&x[(n0 + row) * 256 + kk * 32 + kq * 4];
                ushort4 u;
                u.x = f2bf(v.x); u.y = f2bf(v.y); u.z = f2bf(v.z); u.w = f2bf(v.w);
                *(ushort4*)&Alds[row * 40 + kq * 4] = u;
            }
            {   // B: W1bf chunk 256 rows x 32 k
                int row = i >> 2, seg = i & 3;
                bf16x8 bv = *(const bf16x8*)&W1bf[(size_t)row * 256 + kk * 32 + seg * 8];
                *(bf16x8*)&Blds[row * 40 + seg * 8] = bv;
            }
        }
        __syncthreads();
        bf16x8 a0 = *(const bf16x8*)&Alds[(w * 32 + l15) * 40 + kg * 8];
        bf16x8 a1 = *(const bf16x8*)&Alds[(w * 32 + 16 + l15) * 40 + kg * 8];
        #pragma unroll
        for (int nt = 0; nt < 16; ++nt) {
            bf16x8 b = *(const bf16x8*)&Blds[(nt * 16 + l15) * 40 + kg * 8];
            acc[0][nt] = __builtin_amdgcn_mfma_f32_16x16x32_bf16(a0, b, acc[0][nt], 0, 0, 0);
            acc[1][nt] = __builtin_amdgcn_mfma_f32_16x16x32_bf16(a1, b, acc[1][nt], 0, 0, 0);
        }
    }

    // epilogue: store bf16 h1 (L2 merges the u16 scatter), accumulate channel stats
    float s1[16], s2[16];
    #pragma unroll
    for (int nt = 0; nt < 16; ++nt) { s1[nt] = 0.f; s2[nt] = 0.f; }
    #pragma unroll
    for (int mt = 0; mt < 2; ++mt)
        #pragma unroll
        for (int nt = 0; nt < 16; ++nt)
            #pragma unroll
            for (int r = 0; r < 4; ++r) {
                float f = acc[mt][nt][r];
                size_t row = n0 + w * 32 + mt * 16 + kg * 4 + r;
                h1bf[row * 256 + nt * 16 + l15] = f2bf(f);
                s1[nt] += f;
                s2[nt] += f * f;
            }
    #pragma unroll
    for (int nt = 0; nt < 16; ++nt) {
        s1[nt] += __shfl_xor(s1[nt], 16);
        s1[nt] += __shfl_xor(s1[nt], 32);
        s2[nt] += __shfl_xor(s2[nt], 16);
        s2[nt] += __shfl_xor(s2[nt], 32);
    }
    if (lane < 16) {
        size_t prow = ((size_t)blockIdx.x * 4 + w) * 256;
        #pragma unroll
        for (int nt = 0; nt < 16; ++nt) {
            parts1[prow + nt * 16 + lane] = s1[nt];
            parts2[prow + nt * 16 + lane] = s2[nt];
        }
    }
}

// sum 8192x256 partials -> psum/psum2 (psum pre-zeroed by memset)
__global__ __launch_bounds__(256) void reduce_kernel(
    const float* __restrict__ P1, const float* __restrict__ P2,
    float* __restrict__ psum, float* __restrict__ psum2)
{
    const int t = threadIdx.x;
    const int b = blockIdx.x;
    float s = 0.f, s2 = 0.f;
    for (int r = 0; r < 128; ++r) {
        size_t row = (size_t)(b * 128 + r) * 256;
        s += P1[row + t];
        s2 += P2[row + t];
    }
    atomicAdd(&psum[t], s);
    atomicAdd(&psum2[t], s2);
}

// sc = gamma*rstd ; sh = beta - mu*gamma*rstd
__global__ __launch_bounds__(256) void stats_kernel(
    const float* __restrict__ psum, const float* __restrict__ psum2,
    const float* __restrict__ gamma, const float* __restrict__ beta,
    float* __restrict__ sc, float* __restrict__ sh)
{
    const int t = threadIdx.x;
    const float invN = 1.0f / (float)N_NODES;
    float S = psum[t], S2 = psum2[t];
    float mu = S * invN;
    float var = S2 * invN - mu * mu;
    float rstd = rsqrtf(var + EPS);
    float g = gamma[t] * rstd;
    sc[t] = g;
    sh[t] = beta[t] - mu * g;
}

// ---------------- fused per-graph kernel ----------------
// chunked-LDS logits -> softmax -> A~ -> dot(G) -> tanh
// LDS layout (floats): scS 256 | shS 256 | wfTS 2048 | logitsS 1056 | attnS 1024 |
//                      AtS 2048 | redP 2304 | redS 4 | aSu (bf16) 4224  => 13220 fl = 52.9 KB
__global__ __launch_bounds__(256, 2) void fused_kernel(
    const unsigned short* __restrict__ h1bf, const float* __restrict__ sc_g,
    const float* __restrict__ sh_g, const float* __restrict__ wfT_g,
    const float* __restrict__ bfold, const float* __restrict__ G_g,
    const float* __restrict__ c0_g, float* __restrict__ out)
{
    __shared__ __align__(16) float S[13220];
    float* scS     = S;              // 256
    float* shS     = S + 256;        // 256
    float* wfTS    = S + 512;        // 2048
    float* logitsS = S + 2560;       // 8*132
    float* attnS   = S + 3616;       // 128*8
    float* AtS     = S + 4640;       // 256*8
    float* redP    = S + 6688;       // 256*9
    float* redS    = S + 8992;       // 4
    unsigned short* aSu = (unsigned short*)(S + 8996);   // 32*264 bf16

    const int t = threadIdx.x;
    const int g = blockIdx.x;

    scS[t] = sc_g[t];
    shS[t] = sh_g[t];
    #pragma unroll
    for (int q = 0; q < 8; ++q) wfTS[t + q * 256] = wfT_g[t + q * 256];

    const int n_dot = t & 31, ce = t >> 5;      // dot: 32 nodes x 8 c-slices
    const int h_red = t >> 5, n_red = t & 31;   // reduce: 8 heads x 32 nodes

    for (int chunk = 0; chunk < 4; ++chunk) {
        __syncthreads();   // aS/redP safe; also publishes scS/wfTS on first iter
        // stage 32 nodes: bf16 h1 -> LN+ReLU -> bf16 a into LDS
        #pragma unroll
        for (int p = 0; p < 4; ++p) {
            int i = p * 256 + t;
            int row = i >> 5, seg = i & 31;
            const bf16x8 hv = *(const bf16x8*)&h1bf[((size_t)(g * 128 + chunk * 32 + row)) * 256 + seg * 8];
            float4 sc0 = *(const float4*)&scS[seg * 8];
            float4 sc1 = *(const float4*)&scS[seg * 8 + 4];
            float4 sh0 = *(const float4*)&shS[seg * 8];
            float4 sh1 = *(const float4*)&shS[seg * 8 + 4];
            bf16x8 av;
            av[0] = (short)f2bf(fmaxf(fmaf(bf2f((unsigned short)hv[0]), sc0.x, sh0.x), 0.f));
            av[1] = (short)f2bf(fmaxf(fmaf(bf2f((unsigned short)hv[1]), sc0.y, sh0.y), 0.f));
            av[2] = (short)f2bf(fmaxf(fmaf(bf2f((unsigned short)hv[2]), sc0.z, sh0.z), 0.f));
            av[3] = (short)f2bf(fmaxf(fmaf(bf2f((unsigned short)hv[3]), sc0.w, sh0.w), 0.f));
            av[4] = (short)f2bf(fmaxf(fmaf(bf2f((unsigned short)hv[4]), sc1.x, sh1.x), 0.f));
            av[5] = (short)f2bf(fmaxf(fmaf(bf2f((unsigned short)hv[5]), sc1.y, sh1.y), 0.f));
            av[6] = (short)f2bf(fmaxf(fmaf(bf2f((unsigned short)hv[6]), sc1.z, sh1.z), 0.f));
            av[7] = (short)f2bf(fmaxf(fmaf(bf2f((unsigned short)hv[7]), sc1.w, sh1.w), 0.f));
            *(bf16x8*)&aSu[row * 264 + seg * 8] = av;
        }
        __syncthreads();
        // partial dots: thread (n, ce) covers c in [ce*32, ce*32+32) for all 8 heads
        {
            float lacc[8];
            #pragma unroll
            for (int h = 0; h < 8; ++h) lacc[h] = 0.f;
            #pragma unroll
            for (int i = 0; i < 4; ++i) {
                const bf16x8 a8 = *(const bf16x8*)&aSu[n_dot * 264 + ce * 32 + i * 8];
                float af[8];
                #pragma unroll
                for (int j = 0; j < 8; ++j) af[j] = bf2f((unsigned short)a8[j]);
                #pragma unroll
                for (int h = 0; h < 8; ++h) {
                    const float4 w0 = *(const float4*)&wfTS[h * 256 + ce * 32 + i * 8];
                    const float4 w1 = *(const float4*)&wfTS[h * 256 + ce * 32 + i * 8 + 4];
                    lacc[h] = fmaf(af[0], w0.x, fmaf(af[1], w0.y, fmaf(af[2], w0.z, fmaf(af[3], w0.w,
                              fmaf(af[4], w1.x, fmaf(af[5], w1.y, fmaf(af[6], w1.z, fmaf(af[7], w1.w, lacc[h]))))))));
                }
            }
            #pragma unroll
            for (int h = 0; h < 8; ++h) redP[(ce * 32 + n_dot) * 9 + h] = lacc[h];
        }
        __syncthreads();
        // reduce 8 c-slices -> logits
        {
            float L = bfold[h_red];
            #pragma unroll
            for (int ce2 = 0; ce2 < 8; ++ce2) L += redP[(ce2 * 32 + n_red) * 9 + h_red];
            logitsS[h_red * 132 + chunk * 32 + n_red] = L;
        }
    }
    __syncthreads();

    // softmax per head over 128 nodes (32 threads/head)
    {
        const int head = t >> 5, j = t & 31;
        float l0 = logitsS[head * 132 + j];
        float l1 = logitsS[head * 132 + j + 32];
        float l2 = logitsS[head * 132 + j + 64];
        float l3 = logitsS[head * 132 + j + 96];
        float m = fmaxf(fmaxf(l0, l1), fmaxf(l2, l3));
        for (int s = 16; s > 0; s >>= 1) m = fmaxf(m, __shfl_xor(m, s, 32));
        float p0 = expf(l0 - m), p1 = expf(l1 - m), p2 = expf(l2 - m), p3 = expf(l3 - m);
        float sum = p0 + p1 + p2 + p3;
        for (int s = 16; s > 0; s >>= 1) sum += __shfl_xor(sum, s, 32);
        float inv = 1.0f / sum;
        attnS[(j + 0) * 8 + head] = p0 * inv;
        attnS[(j + 32) * 8 + head] = p1 * inv;
        attnS[(j + 64) * 8 + head] = p2 * inv;
        attnS[(j + 96) * 8 + head] = p3 * inv;
    }
    __syncthreads();

    // A~[h][c=t] = sum_n attn[n,h]*a1[n,t]  (coalesced bf16 re-read of h1)
    {
        float acc[8];
        #pragma unroll
        for (int h = 0; h < 8; ++h) acc[h] = 0.f;
        const float scv = scS[t], shv = shS[t];
        const unsigned short* hp = h1bf + (size_t)g * 128 * 256 + t;
        #pragma unroll 4
        for (int n = 0; n < 128; ++n) {
            float hv = bf2f(hp[n * 256]);
            float a = fmaxf(fmaf(hv, scv, shv), 0.f);
            const float4 w0 = *(const float4*)&attnS[n * 8];
            const float4 w1 = *(const float4*)&attnS[n * 8 + 4];
            acc[0] = fmaf(a, w0.x, acc[0]);
            acc[1] = fmaf(a, w0.y, acc[1]);
            acc[2] = fmaf(a, w0.z, acc[2]);
            acc[3] = fmaf(a, w0.w, acc[3]);
            acc[4] = fmaf(a, w1.x, acc[4]);
            acc[5] = fmaf(a, w1.y, acc[5]);
            acc[6] = fmaf(a, w1.z, acc[6]);
            acc[7] = fmaf(a, w1.w, acc[7]);
        }
        #pragma unroll
        for (int h = 0; h < 8; ++h) AtS[t * 8 + h] = acc[h];
    }
    __syncthreads();

    // r = sum A~*G + c0 ; out = tanh(r)
    {
        float4 a0 = *(const float4*)&AtS[t * 8];
        float4 a1 = *(const float4*)&AtS[t * 8 + 4];
        float4 g0 = *(const float4*)&G_g[t * 8];
        float4 g1 = *(const float4*)&G_g[t * 8 + 4];
        float term = a0.x * g0.x + a0.y * g0.y + a0.z * g0.z + a0.w * g0.w +
                     a1.x * g1.x + a1.y * g1.y + a1.z * g1.z + a1.w * g1.w;
        for (int s = 32; s > 0; s >>= 1) term += __shfl_xor(term, s);
        if ((t & 63) == 0) redS[t >> 6] = term;
        __syncthreads();
        if (t == 0) out[g] = tanhf(redS[0] + redS[1] + redS[2] + redS[3] + c0_g[0]);
    }
}

// ---------------- launch ----------------
// ws layout: h1bf (N*C ushort, 128 MiB) | W1bf (64K ushort) | float region
#define FOFF_WKE 0
#define FOFF_LB  2048      // 8, pad to 16
#define FOFF_WFT 2064      // 2048
#define FOFF_BFD 4112      // 8, pad to 16
#define FOFF_WOR 4128      // 256
#define FOFF_V   4384      // 2048
#define FOFF_G   6432      // 2048
#define FOFF_C0  8480      // 4
#define FOFF_PS  8484      // 256
#define FOFF_PS2 8740      // 256
#define FOFF_SC  8996      // 256
#define FOFF_SH  9252      // 256, pad to 9512
#define FOFF_P1  9512      // 8192*256
#define FOFF_P2  (9512 + 2097152)

extern "C" void kernel_launch(void* const* d_in, const int* in_sizes, int n_in,
                              void* d_out, int out_size, void* d_ws, size_t ws_size,
                              hipStream_t stream)
{
    (void)in_sizes; (void)n_in; (void)out_size; (void)ws_size;
    const float* x     = (const float*)d_in[0];
    const float* W1    = (const float*)d_in[3];
    // d_in[4] = b1: cancels exactly through the batch-mean subtraction in LN
    const float* gamma = (const float*)d_in[5];
    const float* beta  = (const float*)d_in[6];
    const float* W2    = (const float*)d_in[7];
    const float* b2    = (const float*)d_in[8];
    const float* Wq    = (const float*)d_in[9];
    const float* bq    = (const float*)d_in[10];
    const float* Wk    = (const float*)d_in[11];
    const float* bk    = (const float*)d_in[12];
    const float* Wv    = (const float*)d_in[13];
    const float* bv    = (const float*)d_in[14];
    const float* Wo    = (const float*)d_in[15];
    const float* bo    = (const float*)d_in[16];
    const float* Wr    = (const float*)d_in[17];
    const float* br    = (const float*)d_in[18];

    unsigned short* h1bf = (unsigned short*)d_ws;
    unsigned short* W1bf = h1bf + (size_t)N_NODES * 256;
    float* fbase = (float*)(W1bf + 65536);

    float* wk_eff = fbase + FOFF_WKE;
    float* lbias  = fbase + FOFF_LB;
    float* wfT    = fbase + FOFF_WFT;
    float* bfold  = fbase + FOFF_BFD;
    float* wor    = fbase + FOFF_WOR;
    float* V_g    = fbase + FOFF_V;
    float* G_g    = fbase + FOFF_G;
    float* c0     = fbase + FOFF_C0;
    float* psum   = fbase + FOFF_PS;
    float* psum2  = fbase + FOFF_PS2;
    float* sc     = fbase + FOFF_SC;
    float* sh     = fbase + FOFF_SH;
    float* P1     = fbase + FOFF_P1;
    float* P2     = fbase + FOFF_P2;

    hipMemsetAsync((void*)psum, 0, 512 * sizeof(float), stream);

    hipLaunchKernelGGL(prep1_kernel, dim3(1), dim3(256), 0, stream,
                       Wq, bq, Wk, bk, Wo, Wr, wk_eff, lbias, wor);
    hipLaunchKernelGGL(w1cvt_kernel, dim3(256), dim3(256), 0, stream, W1, W1bf);
    hipLaunchKernelGGL(prep2_kernel, dim3(8), dim3(256), 0, stream,
                       W2, b2, Wv, wk_eff, lbias, wor, wfT, bfold, V_g);
    hipLaunchKernelGGL(prep3_kernel, dim3(8), dim3(256), 0, stream, W2, V_g, G_g);
    hipLaunchKernelGGL(prep4_kernel, dim3(1), dim3(256), 0, stream,
                       b2, bv, bo, Wr, br, V_g, wor, c0);
    hipLaunchKernelGGL(gemm1_kernel, dim3(N_NODES / 128), dim3(256), 0, stream,
                       x, W1bf, h1bf, P1, P2);
    hipLaunchKernelGGL(reduce_kernel, dim3(64), dim3(256), 0, stream, P1, P2, psum, psum2);
    hipLaunchKernelGGL(stats_kernel, dim3(1), dim3(256), 0, stream,
                       psum, psum2, gamma, beta, sc, sh);
    hipLaunchKernelGGL(fused_kernel, dim3(B_GRAPHS), dim3(256), 0, stream,
                       h1bf, sc, sh, wfT, bfold, G_g, c0, (float*)d_out);
}

// Round 4
// 588.214 us; speedup vs baseline: 1.5958x; 1.1000x over previous
//
#include <hip/hip_runtime.h>
#include <hip/hip_bf16.h>
#include <math.h>

#define C_DIM 256
#define H_HEADS 8
#define B_GRAPHS 2048
#define NPG 128
#define N_NODES (B_GRAPHS * NPG)   // 262144
#define EPS 1e-5f
#define SCALE_ATT 0.17677669529663687f   // 1/sqrt(32)
#define AST 264                          // u16 stride of LDS a-tile rows

typedef short bf16x8 __attribute__((ext_vector_type(8)));
typedef float f32x4 __attribute__((ext_vector_type(4)));

__device__ __forceinline__ unsigned short f2bf(float f) {
    __hip_bfloat16 h = __float2bfloat16(f);
    union { __hip_bfloat16 h; unsigned short u; } cv; cv.h = h; return cv.u;
}
__device__ __forceinline__ float bf2f(unsigned short u) {
    union { unsigned int i; float f; } v; v.i = ((unsigned int)u) << 16; return v.f;
}

// ---------------- prep kernels ----------------

// qh = rowsum(Wq)+bq ; wk_eff[head,c'] = scale * sum_d Wk[head*32+d,c']*qh[head*32+d]
// wor[j] = sum_j2 Wo[j2,j]*Wr[j2]     (bfold dropped: per-head const cancels in softmax)
__global__ __launch_bounds__(256) void prep1_kernel(
    const float* __restrict__ Wq, const float* __restrict__ bq,
    const float* __restrict__ Wk,
    const float* __restrict__ Wo, const float* __restrict__ Wr,
    float* __restrict__ wk_eff, float* __restrict__ wor)
{
    __shared__ float qhS[256];
    __shared__ float WrS[256];
    const int t = threadIdx.x;
    {
        float s = bq[t];
        const float* row = Wq + (size_t)t * 256;
        for (int c = 0; c < 256; c += 4) {
            float4 v = *(const float4*)&row[c];
            s += v.x + v.y + v.z + v.w;
        }
        qhS[t] = s;
        WrS[t] = Wr[t];
    }
    __syncthreads();
    for (int it = 0; it < 8; ++it) {
        int idx = t + it * 256;
        int head = idx >> 8, c = idx & 255;
        float acc = 0.f;
        #pragma unroll 4
        for (int d = 0; d < 32; ++d)
            acc = fmaf(Wk[(size_t)(head * 32 + d) * 256 + c], qhS[head * 32 + d], acc);
        wk_eff[head * 256 + c] = acc * SCALE_ATT;
    }
    {
        float acc = 0.f;
        for (int j2 = 0; j2 < 256; ++j2)
            acc = fmaf(Wo[(size_t)j2 * 256 + t], WrS[j2], acc);
        wor[t] = acc;
    }
}

// WBg[head][c] (bf16) = wfold[head][c] = sum_c' W2[c',c]*wk_eff[head,c'];  V[head,c']
__global__ __launch_bounds__(256) void prep2_kernel(
    const float* __restrict__ W2, const float* __restrict__ Wv,
    const float* __restrict__ wk_eff, const float* __restrict__ wor_g,
    unsigned short* __restrict__ WBg, float* __restrict__ V_g)
{
    __shared__ float wkS[256];
    const int t = threadIdx.x, head = blockIdx.x;
    wkS[t] = wk_eff[head * 256 + t];
    __syncthreads();
    float acc = 0.f;
    #pragma unroll 4
    for (int cp = 0; cp < 256; ++cp)
        acc = fmaf(W2[(size_t)cp * 256 + t], wkS[cp], acc);
    WBg[head * 256 + t] = f2bf(acc);
    float accv = 0.f;
    #pragma unroll 4
    for (int d = 0; d < 32; ++d) {
        int j = head * 32 + d;
        accv = fmaf(Wv[(size_t)j * 256 + t], wor_g[j], accv);
    }
    V_g[head * 256 + t] = accv;
}

// WBg[8+head][c] (bf16) = G[head][c] = sum_c' W2[c',c]*V[head,c']
__global__ __launch_bounds__(256) void prep3_kernel(
    const float* __restrict__ W2, const float* __restrict__ V_g,
    unsigned short* __restrict__ WBg)
{
    __shared__ float vS[256];
    const int t = threadIdx.x, head = blockIdx.x;
    vS[t] = V_g[head * 256 + t];
    __syncthreads();
    float acc = 0.f;
    #pragma unroll 4
    for (int cp = 0; cp < 256; ++cp)
        acc = fmaf(W2[(size_t)cp * 256 + t], vS[cp], acc);
    WBg[(8 + head) * 256 + t] = f2bf(acc);
}

// c0 = sum b2*(sum_h V) + sum bv*wor + sum bo*Wr + br
__global__ __launch_bounds__(256) void prep4_kernel(
    const float* __restrict__ b2, const float* __restrict__ bv,
    const float* __restrict__ bo, const float* __restrict__ Wr,
    const float* __restrict__ br, const float* __restrict__ V_g,
    const float* __restrict__ wor, float* __restrict__ c0)
{
    __shared__ float red[256];
    const int t = threadIdx.x;
    float vs = 0.f;
    #pragma unroll
    for (int h = 0; h < 8; ++h) vs += V_g[h * 256 + t];
    red[t] = b2[t] * vs + bv[t] * wor[t] + bo[t] * Wr[t];
    __syncthreads();
    for (int s = 128; s > 0; s >>= 1) {
        if (t < s) red[t] += red[t + s];
        __syncthreads();
    }
    if (t == 0) c0[0] = red[0] + br[0];
}

// W1 fp32 -> bf16 ([j][k] row-major = MFMA B-operand feed layout)
__global__ __launch_bounds__(256) void w1cvt_kernel(
    const float* __restrict__ W1, unsigned short* __restrict__ W1bf)
{
    int i = blockIdx.x * 256 + threadIdx.x;
    W1bf[i] = f2bf(W1[i]);
}

// ---------------- GEMM1 (MFMA bf16): h1 = x @ W1^T (b1 cancels through LN) ----------------
// 128 rows x 256 cols per block. h1 stored bf16 SWIZZLED: element (n,c) at
// h1s[(n>>2)*1024 + c*4 + (n&3)]  -> lane stores its 4 acc rows as one ushort4.
__global__ __launch_bounds__(256) void gemm1_kernel(
    const float* __restrict__ x, const unsigned short* __restrict__ W1bf,
    unsigned short* __restrict__ h1s,
    float* __restrict__ parts1, float* __restrict__ parts2)
{
    __shared__ unsigned short Alds[128 * 40];   // 10 KB
    __shared__ unsigned short Blds[256 * 40];   // 20.5 KB
    const int t = threadIdx.x;
    const int lane = t & 63, w = t >> 6;
    const int l15 = lane & 15, kg = lane >> 4;
    const size_t n0 = (size_t)blockIdx.x * 128;

    f32x4 acc[2][16];
    #pragma unroll
    for (int mt = 0; mt < 2; ++mt)
        #pragma unroll
        for (int nt = 0; nt < 16; ++nt)
            acc[mt][nt] = (f32x4){0.f, 0.f, 0.f, 0.f};

    for (int kk = 0; kk < 8; ++kk) {
        if (kk) __syncthreads();
        #pragma unroll
        for (int p = 0; p < 4; ++p) {
            int i = p * 256 + t;
            {   // A: x chunk 128 rows x 32 k fp32 -> bf16 LDS
                int row = i >> 3, kq = i & 7;
                float4 v = *(const float4*)&x[(n0 + row) * 256 + kk * 32 + kq * 4];
                ushort4 u;
                u.x = f2bf(v.x); u.y = f2bf(v.y); u.z = f2bf(v.z); u.w = f2bf(v.w);
                *(ushort4*)&Alds[row * 40 + kq * 4] = u;
            }
            {   // B: W1bf chunk 256 rows x 32 k
                int row = i >> 2, seg = i & 3;
                bf16x8 bv = *(const bf16x8*)&W1bf[(size_t)row * 256 + kk * 32 + seg * 8];
                *(bf16x8*)&Blds[row * 40 + seg * 8] = bv;
            }
        }
        __syncthreads();
        bf16x8 a0 = *(const bf16x8*)&Alds[(w * 32 + l15) * 40 + kg * 8];
        bf16x8 a1 = *(const bf16x8*)&Alds[(w * 32 + 16 + l15) * 40 + kg * 8];
        #pragma unroll
        for (int nt = 0; nt < 16; ++nt) {
            bf16x8 b = *(const bf16x8*)&Blds[(nt * 16 + l15) * 40 + kg * 8];
            acc[0][nt] = __builtin_amdgcn_mfma_f32_16x16x32_bf16(a0, b, acc[0][nt], 0, 0, 0);
            acc[1][nt] = __builtin_amdgcn_mfma_f32_16x16x32_bf16(a1, b, acc[1][nt], 0, 0, 0);
        }
    }

    // epilogue: packed swizzled stores + channel stats
    float s1[16], s2[16];
    #pragma unroll
    for (int nt = 0; nt < 16; ++nt) { s1[nt] = 0.f; s2[nt] = 0.f; }
    const size_t rowqBase = (n0 >> 2) + (size_t)w * 8;
    #pragma unroll
    for (int mt = 0; mt < 2; ++mt)
        #pragma unroll
        for (int nt = 0; nt < 16; ++nt) {
            float f0 = acc[mt][nt][0], f1 = acc[mt][nt][1];
            float f2v = acc[mt][nt][2], f3 = acc[mt][nt][3];
            s1[nt] += (f0 + f1) + (f2v + f3);
            s2[nt] += (f0 * f0 + f1 * f1) + (f2v * f2v + f3 * f3);
            ushort4 u;
            u.x = f2bf(f0); u.y = f2bf(f1); u.z = f2bf(f2v); u.w = f2bf(f3);
            *(ushort4*)&h1s[(rowqBase + mt * 4 + kg) * 1024 + (nt * 16 + l15) * 4] = u;
        }
    #pragma unroll
    for (int nt = 0; nt < 16; ++nt) {
        s1[nt] += __shfl_xor(s1[nt], 16);
        s1[nt] += __shfl_xor(s1[nt], 32);
        s2[nt] += __shfl_xor(s2[nt], 16);
        s2[nt] += __shfl_xor(s2[nt], 32);
    }
    if (lane < 16) {
        size_t prow = ((size_t)blockIdx.x * 4 + w) * 256;
        #pragma unroll
        for (int nt = 0; nt < 16; ++nt) {
            parts1[prow + nt * 16 + lane] = s1[nt];
            parts2[prow + nt * 16 + lane] = s2[nt];
        }
    }
}

// sum 8192x256 partials -> psum/psum2 (psum pre-zeroed by memset)
__global__ __launch_bounds__(256) void reduce_kernel(
    const float* __restrict__ P1, const float* __restrict__ P2,
    float* __restrict__ psum, float* __restrict__ psum2)
{
    const int t = threadIdx.x;
    const int b = blockIdx.x;
    float s = 0.f, s2 = 0.f;
    for (int r = 0; r < 128; ++r) {
        size_t row = (size_t)(b * 128 + r) * 256;
        s += P1[row + t];
        s2 += P2[row + t];
    }
    atomicAdd(&psum[t], s);
    atomicAdd(&psum2[t], s2);
}

// sc = gamma*rstd ; sh = beta - mu*gamma*rstd
__global__ __launch_bounds__(256) void stats_kernel(
    const float* __restrict__ psum, const float* __restrict__ psum2,
    const float* __restrict__ gamma, const float* __restrict__ beta,
    float* __restrict__ sc, float* __restrict__ sh)
{
    const int t = threadIdx.x;
    const float invN = 1.0f / (float)N_NODES;
    float S = psum[t], S2 = psum2[t];
    float mu = S * invN;
    float var = S2 * invN - mu * mu;
    float rstd = rsqrtf(var + EPS);
    float g = gamma[t] * rstd;
    sc[t] = g;
    sh[t] = beta[t] - mu * g;
}

// ---------------- fused per-graph kernel ----------------
// one block per graph: stage a=ReLU(LN(h1)) to LDS (single h1 read) ->
// one MFMA GEMM [128x256]@[256x16] giving logits (j<8) and gdot (j>=8) ->
// r = sum_h (sum_n p*gdot)/(sum_n p) + c0 ; out = tanh(r).
__global__ __launch_bounds__(256, 1) void fused_kernel(
    const unsigned short* __restrict__ h1s, const float* __restrict__ sc_g,
    const float* __restrict__ sh_g, const unsigned short* __restrict__ WBg,
    const float* __restrict__ c0_g, float* __restrict__ out)
{
    __shared__ __align__(16) unsigned short aS[128 * AST];   // 67.6 KB
    __shared__ __align__(16) unsigned short WBl[16 * AST];   // 8.4 KB
    __shared__ float scS[256], shS[256];
    __shared__ float LG[128 * 17];                           // 8.7 KB
    __shared__ float redH[8];
    __shared__ float c0S;

    const int t = threadIdx.x;
    const int g = blockIdx.x;
    const int lane = t & 63, w = t >> 6;
    const int l15 = lane & 15, kg = lane >> 4;

    scS[t] = sc_g[t];
    shS[t] = sh_g[t];
    {   // load 16x256 bf16 weight block (logits + gdot heads)
        int j = t >> 4, cc = (t & 15) * 16;
        bf16x8 w0 = *(const bf16x8*)&WBg[j * 256 + cc];
        bf16x8 w1 = *(const bf16x8*)&WBg[j * 256 + cc + 8];
        *(bf16x8*)&WBl[j * AST + cc] = w0;
        *(bf16x8*)&WBl[j * AST + cc + 8] = w1;
    }
    if (t == 0) c0S = c0_g[0];
    __syncthreads();

    // stage: swizzled h1 -> LN+ReLU -> aS[n][c] (bf16, row stride AST)
    // 128x256 tile = 32 rowq x 1024 u16 = 4096 bf16x8 chunks; 16 iters x 256 thr.
    // chunk (rowq, cp) decodes to cols {cp*2, cp*2+1}, rows rowq*4 + 0..3.
    const unsigned short* hg = h1s + (size_t)g * 32768;
    unsigned int* aS32 = (unsigned int*)aS;
    #pragma unroll 4
    for (int it = 0; it < 16; ++it) {
        int i = it * 256 + t;
        int rowq = i >> 7, cp = i & 127, cc0 = cp * 2;
        bf16x8 hv = *(const bf16x8*)&hg[rowq * 1024 + cp * 8];
        float sc0 = scS[cc0], sc1 = scS[cc0 + 1];
        float sh0 = shS[cc0], sh1 = shS[cc0 + 1];
        #pragma unroll
        for (int r = 0; r < 4; ++r) {
            float a0 = fmaxf(fmaf(bf2f((unsigned short)hv[r]), sc0, sh0), 0.f);
            float a1 = fmaxf(fmaf(bf2f((unsigned short)hv[r + 4]), sc1, sh1), 0.f);
            unsigned int pk = (unsigned int)f2bf(a0) | ((unsigned int)f2bf(a1) << 16);
            aS32[((rowq * 4 + r) * AST + cc0) >> 1] = pk;
        }
    }
    __syncthreads();

    // MFMA: wave w covers rows [w*32, w*32+32)
    {
        const int m0 = w * 32;
        f32x4 acc0 = {0.f, 0.f, 0.f, 0.f}, acc1 = {0.f, 0.f, 0.f, 0.f};
        #pragma unroll
        for (int kt = 0; kt < 8; ++kt) {
            bf16x8 b  = *(const bf16x8*)&WBl[l15 * AST + kt * 32 + kg * 8];
            bf16x8 a0 = *(const bf16x8*)&aS[(m0 + l15) * AST + kt * 32 + kg * 8];
            bf16x8 a1 = *(const bf16x8*)&aS[(m0 + 16 + l15) * AST + kt * 32 + kg * 8];
            acc0 = __builtin_amdgcn_mfma_f32_16x16x32_bf16(a0, b, acc0, 0, 0, 0);
            acc1 = __builtin_amdgcn_mfma_f32_16x16x32_bf16(a1, b, acc1, 0, 0, 0);
        }
        #pragma unroll
        for (int r = 0; r < 4; ++r) {
            LG[(m0 + kg * 4 + r) * 17 + l15] = acc0[r];
            LG[(m0 + 16 + kg * 4 + r) * 17 + l15] = acc1[r];
        }
    }
    __syncthreads();

    // per-head: softmax-weighted gdot (bfold cancels; no attn materialization)
    {
        const int h = t >> 5, j = t & 31;
        float l[4], gv[4];
        #pragma unroll
        for (int q = 0; q < 4; ++q) {
            int n = j + q * 32;
            l[q]  = LG[n * 17 + h];
            gv[q] = LG[n * 17 + 8 + h];
        }
        float m = fmaxf(fmaxf(l[0], l[1]), fmaxf(l[2], l[3]));
        for (int s = 16; s > 0; s >>= 1) m = fmaxf(m, __shfl_xor(m, s, 32));
        float sp = 0.f, sg = 0.f;
        #pragma unroll
        for (int q = 0; q < 4; ++q) {
            float p = expf(l[q] - m);
            sp += p;
            sg = fmaf(p, gv[q], sg);
        }
        for (int s = 16; s > 0; s >>= 1) {
            sp += __shfl_xor(sp, s, 32);
            sg += __shfl_xor(sg, s, 32);
        }
        if (j == 0) redH[h] = sg / sp;
    }
    __syncthreads();
    if (t == 0) {
        float r = c0S;
        #pragma unroll
        for (int h = 0; h < 8; ++h) r += redH[h];
        out[g] = tanhf(r);
    }
}

// ---------------- launch ----------------
// ws: h1s (N*256 u16) | W1bf (65536 u16) | WBg (4096 u16) | float region
#define FOFF_WKE 0
#define FOFF_WOR 2048
#define FOFF_V   2304
#define FOFF_C0  4352
#define FOFF_PS  4368
#define FOFF_PS2 4624
#define FOFF_SC  4880
#define FOFF_SH  5136
#define FOFF_P1  5392
#define FOFF_P2  (5392 + 2097152)

extern "C" void kernel_launch(void* const* d_in, const int* in_sizes, int n_in,
                              void* d_out, int out_size, void* d_ws, size_t ws_size,
                              hipStream_t stream)
{
    (void)in_sizes; (void)n_in; (void)out_size; (void)ws_size;
    const float* x     = (const float*)d_in[0];
    const float* W1    = (const float*)d_in[3];
    // d_in[4] = b1: cancels exactly through the batch-mean subtraction in LN
    const float* gamma = (const float*)d_in[5];
    const float* beta  = (const float*)d_in[6];
    const float* W2    = (const float*)d_in[7];
    const float* b2    = (const float*)d_in[8];
    const float* Wq    = (const float*)d_in[9];
    const float* bq    = (const float*)d_in[10];
    const float* Wk    = (const float*)d_in[11];
    const float* Wv    = (const float*)d_in[13];
    const float* bv    = (const float*)d_in[14];
    const float* Wo    = (const float*)d_in[15];
    const float* bo    = (const float*)d_in[16];
    const float* Wr    = (const float*)d_in[17];
    const float* br    = (const float*)d_in[18];

    unsigned short* h1s  = (unsigned short*)d_ws;
    unsigned short* W1bf = h1s + (size_t)N_NODES * 256;
    unsigned short* WBg  = W1bf + 65536;
    float* fbase = (float*)(WBg + 4096);

    float* wk_eff = fbase + FOFF_WKE;
    float* wor    = fbase + FOFF_WOR;
    float* V_g    = fbase + FOFF_V;
    float* c0     = fbase + FOFF_C0;
    float* psum   = fbase + FOFF_PS;
    float* psum2  = fbase + FOFF_PS2;
    float* sc     = fbase + FOFF_SC;
    float* sh     = fbase + FOFF_SH;
    float* P1     = fbase + FOFF_P1;
    float* P2     = fbase + FOFF_P2;

    hipMemsetAsync((void*)psum, 0, 512 * sizeof(float), stream);

    hipLaunchKernelGGL(prep1_kernel, dim3(1), dim3(256), 0, stream,
                       Wq, bq, Wk, Wo, Wr, wk_eff, wor);
    hipLaunchKernelGGL(w1cvt_kernel, dim3(256), dim3(256), 0, stream, W1, W1bf);
    hipLaunchKernelGGL(prep2_kernel, dim3(8), dim3(256), 0, stream,
                       W2, Wv, wk_eff, wor, WBg, V_g);
    hipLaunchKernelGGL(prep3_kernel, dim3(8), dim3(256), 0, stream, W2, V_g, WBg);
    hipLaunchKernelGGL(prep4_kernel, dim3(1), dim3(256), 0, stream,
                       b2, bv, bo, Wr, br, V_g, wor, c0);
    hipLaunchKernelGGL(gemm1_kernel, dim3(N_NODES / 128), dim3(256), 0, stream,
                       x, W1bf, h1s, P1, P2);
    hipLaunchKernelGGL(reduce_kernel, dim3(64), dim3(256), 0, stream, P1, P2, psum, psum2);
    hipLaunchKernelGGL(stats_kernel, dim3(1), dim3(256), 0, stream,
                       psum, psum2, gamma, beta, sc, sh);
    hipLaunchKernelGGL(fused_kernel, dim3(B_GRAPHS), dim3(256), 0, stream,
                       h1s, sc, sh, WBg, c0, (float*)d_out);
}